// Round 8
// baseline (2202.957 us; speedup 1.0000x reference)
//
#include <hip/hip_runtime.h>

// ---------------- types / helpers ----------------
typedef unsigned short u16;
typedef unsigned int   u32;
typedef __bf16 bf16x8 __attribute__((ext_vector_type(8)));
typedef float  f32x4  __attribute__((ext_vector_type(4)));

__device__ __forceinline__ u16 f2bf(float f) {
    u32 u = __builtin_bit_cast(u32, f);
    u = u + 0x7fffu + ((u >> 16) & 1u);
    return (u16)(u >> 16);
}
__device__ __forceinline__ float bflo(u32 u) { return __builtin_bit_cast(float, u << 16); }
__device__ __forceinline__ float bfhi(u32 u) { return __builtin_bit_cast(float, u & 0xffff0000u); }
__device__ __forceinline__ u32 pack2(float x, float y) { return (u32)f2bf(x) | ((u32)f2bf(y) << 16); }

// global -> LDS direct copy, 16B per lane. LDS dest is wave-uniform base (+lane*16 by HW).
__device__ __forceinline__ void gll16(const u16* g, u16* l) {
    __builtin_amdgcn_global_load_lds(
        (const __attribute__((address_space(1))) void*)g,
        (__attribute__((address_space(3))) void*)l, 16, 0, 0);
}

#define NN 100000
#define EE 400000
#define DP 320   // padded D (300 -> 320)
#define HP 640   // padded 2D (600 -> 640)

// ---------------- preprocessing ----------------
__global__ void count_deg(const int* __restrict__ ei, int* __restrict__ deg, int E) {
    int e = blockIdx.x * 256 + threadIdx.x;
    if (e < E) atomicAdd(&deg[ei[E + e]], 1);
}

__global__ void scan1(const int* __restrict__ deg, int* __restrict__ out, int* __restrict__ bsums, int n) {
    __shared__ int lds[1024];
    int t = threadIdx.x;
    int i = blockIdx.x * 1024 + t;
    int v = (i < n) ? deg[i] : 0;
    lds[t] = v;
    __syncthreads();
    for (int d = 1; d < 1024; d <<= 1) {
        int add = (t >= d) ? lds[t - d] : 0;
        __syncthreads();
        lds[t] += add;
        __syncthreads();
    }
    if (i < n) out[i] = lds[t] - v;   // exclusive
    if (t == 1023) bsums[blockIdx.x] = lds[t];
}

__global__ void scan2(int* __restrict__ bsums, int nb) {
    __shared__ int lds[128];
    int t = threadIdx.x;
    int v = (t < nb) ? bsums[t] : 0;
    lds[t] = v;
    __syncthreads();
    for (int d = 1; d < 128; d <<= 1) {
        int add = (t >= d) ? lds[t - d] : 0;
        __syncthreads();
        lds[t] += add;
        __syncthreads();
    }
    if (t < nb) bsums[t] = lds[t] - v;
}

__global__ void scan3(int* __restrict__ out, const int* __restrict__ bsums, int n, int etot) {
    int i = blockIdx.x * 1024 + threadIdx.x;
    if (i < n) out[i] += bsums[blockIdx.x];
    else if (i == n) out[i] = etot;
}

__global__ void fill_csr(const int* __restrict__ ei, const int* __restrict__ ea,
                         int* __restrict__ cursors, u32* __restrict__ vals, int E) {
    int e = blockIdx.x * 256 + threadIdx.x;
    if (e >= E) return;
    int dst = ei[E + e];
    int src = ei[e];
    u32 code = (u32)((ea[e*4] & 1) | ((ea[e*4+1] & 1) << 1) | ((ea[e*4+2] & 1) << 2) | ((ea[e*4+3] & 1) << 3));
    int pos = atomicAdd(&cursors[dst], 1);
    vals[pos] = ((u32)src << 4) | code;
}

// W1 -> transposed padded bf16, pre-swizzled image (XOR of 16B-unit index with n&7 within row).
// fused_mlp stages linearly into LDS and applies the same XOR on read -> 2-way banks.
__global__ void conv_w1(const float* __restrict__ w, u16* __restrict__ wt) {
    int id = blockIdx.x * 256 + threadIdx.x;
    if (id >= 5 * HP * DP) return;
    int l = id / (HP * DP);
    int rem = id - l * (HP * DP);
    int n = rem / DP;
    int kidx = rem - n * DP;
    int u = kidx >> 3, e = kidx & 7;
    int kk = ((u ^ (n & 7)) << 3) | e;
    u16 v = 0;
    if (n < 600 && kk < 300) v = f2bf(w[((size_t)l * 300 + kk) * 600 + n]);
    wt[id] = v;
}
// W2 -> [320 n][640 k] bf16, pre-swizzled: within each 4-unit (32-k) chunk group,
// physical unit u2 holds logical unit u2 ^ ((n>>1)&3).  Read applies the same XOR.
__global__ void conv_w2(const float* __restrict__ w, u16* __restrict__ wt) {
    int id = blockIdx.x * 256 + threadIdx.x;
    if (id >= 5 * DP * HP) return;
    int l = id / (DP * HP);
    int rem = id - l * (DP * HP);
    int n = rem / HP;
    int kp = rem - n * HP;
    int up = kp >> 3, e = kp & 7;
    int ul = (up & ~3) | ((up & 3) ^ ((n >> 1) & 3));
    int kk = (ul << 3) | e;
    u16 v = 0;
    if (n < 300 && kk < 600) v = f2bf(w[((size_t)l * 600 + kk) * 300 + n]);
    wt[id] = v;
}

// atom encoder -> y bf16
__global__ void atom_enc(const int* __restrict__ x, const float* __restrict__ at, u16* __restrict__ y) {
    const int i = blockIdx.x;
    const int d = threadIdx.x; // 0..319
    __shared__ int xi[7];
    if (d < 7) xi[d] = x[i * 7 + d];
    __syncthreads();
    u16 v = 0;
    if (d < 300) {
        float s = 0.f;
        #pragma unroll
        for (int f = 0; f < 7; ++f) s += at[(f * 119 + xi[f]) * 300 + d];
        v = f2bf(s);
    }
    y[(size_t)i * DP + d] = v;
}

// per-layer bond embedding table: 16 codes + self-loop (index 16)
__global__ void bond_enc(const float* __restrict__ bt, float* __restrict__ emb) {
    const int c = blockIdx.x;  // 0..16
    const int d = threadIdx.x; // 0..319
    float s = 0.f;
    if (d < 300) {
        if (c < 16) {
            #pragma unroll
            for (int f = 0; f < 4; ++f) s += bt[(f * 6 + ((c >> f) & 1)) * 300 + d];
        } else {
            s = bt[4 * 300 + d];  // bond[0][4]
            #pragma unroll
            for (int f = 1; f < 4; ++f) s += bt[f * 6 * 300 + d];
        }
    }
    emb[c * DP + d] = s;
}

// stats -> BN (scale, shift)
__global__ void bn_ss(const float* __restrict__ stats, const float* __restrict__ gamma,
                      const float* __restrict__ beta, float* __restrict__ scale,
                      float* __restrict__ shift, int n) {
    int d = threadIdx.x;
    float sc = 0.f, sh = 0.f;
    if (d < 300) {
        float inv_n = 1.0f / (float)n;
        float mu = stats[d] * inv_n;
        float var = stats[DP + d] * inv_n - mu * mu;
        float inv = 1.0f / sqrtf(var + 1e-5f);
        sc = gamma[d] * inv;
        sh = beta[d] - mu * sc;
    }
    scale[d] = sc; shift[d] = sh;
}

// y[i][d] = bf16(relu(scale*h_raw + shift))
__global__ void bn_apply(const float* __restrict__ hraw, const float* __restrict__ scale,
                         const float* __restrict__ shift, u16* __restrict__ y) {
    const int i = blockIdx.x;
    const int d = threadIdx.x;
    float v = fmaf(scale[d], hraw[(size_t)i * DP + d], shift[d]);
    y[(size_t)i * DP + d] = f2bf(fmaxf(v, 0.f));
}

// ---------------- aggregation: one wave per node, uint4 gathers ----------------
__global__ void aggregate(const u16* __restrict__ y,
                          const float* __restrict__ emb,
                          const int* __restrict__ offs, const u32* __restrict__ vals,
                          u16* __restrict__ agg, const int n) {
    const int wid = (int)((blockIdx.x * (size_t)blockDim.x + threadIdx.x) >> 6);
    const int lane = threadIdx.x & 63;
    if (wid >= n) return;
    const bool act = (lane < 40);

    float acc[8];
    #pragma unroll
    for (int i = 0; i < 8; ++i) acc[i] = 0.f;

    auto accum = [&](int srcrow, const float* erow) {
        if (act) {
            uint4 v = *(const uint4*)(y + (size_t)srcrow * DP + lane * 8);
            float4 e0 = *(const float4*)(erow + lane * 8);
            float4 e1 = *(const float4*)(erow + lane * 8 + 4);
            acc[0] += bflo(v.x) + e0.x;  acc[1] += bfhi(v.x) + e0.y;
            acc[2] += bflo(v.y) + e0.z;  acc[3] += bfhi(v.y) + e0.w;
            acc[4] += bflo(v.z) + e1.x;  acc[5] += bfhi(v.z) + e1.y;
            acc[6] += bflo(v.w) + e1.z;  acc[7] += bfhi(v.w) + e1.w;
        }
    };

    accum(wid, emb + 16 * DP);            // self loop
    const int s = offs[wid], t = offs[wid + 1];
    for (int e = s; e < t; ++e) {
        u32 v = vals[e];
        accum((int)(v >> 4), emb + (v & 15u) * DP);
    }

    if (act) {
        uint4 o;
        o.x = pack2(acc[0], acc[1]);
        o.y = pack2(acc[2], acc[3]);
        o.z = pack2(acc[4], acc[5]);
        o.w = pack2(acc[6], acc[7]);
        *(uint4*)(agg + (size_t)wid * DP + lane * 8) = o;
    }
}

// ---------------- fused MLP: depth-2 pipeline + COUNTED VMCNT (T4) ----------------
// Same geometry/buffers as r7 (verified correct).  Sync protocol changed to the
// m201 pattern: the per-phase barrier NO LONGER drains vmcnt.  Phase c:
//   {vmcnt(5) [own S(c-1) landed] + lgkmcnt(0); s_barrier; sched_barrier;
//    issue S(c) = {W1(c+1), W2(c)} -> parity pc^1  (5 gll/wave, flat map:
//    waves 0-3 stage W1, waves 4-7 stage W2);
//    GEMM2(c-1) [hidF[pc^1], W2s[pc]]; GEMM1(c) [W1s[pc]]; hidF[pc] write}
// S(c)'s loads stay in flight ACROSS the barrier with a full phase of compute
// cover; only the issuing wave's own 5 loads are confirmed at c+1 (vmcnt(5)),
// all other waves' by their own waits + the barrier.
// Race-safety: S(c) targets parity pc^1, last read in phase c-1; S(c) is issued
// after the top-of-c barrier, so all waves have left phase c-1.  b1 is preloaded
// to LDS so no in-loop global load perturbs vmcnt bookkeeping.
// LDS 121,344 B -> 1 block/CU.
__global__ __launch_bounds__(512, 2) void fused_mlp(
    const u16* __restrict__ A,      // agg [N][320] bf16
    const u16* __restrict__ W1t,    // [640][320] bf16, swizzled image
    const u16* __restrict__ W2t,    // [320][640] bf16, swizzled image
    const float* __restrict__ b1g,  // [600]
    const float* __restrict__ b2g,  // [300]
    float* __restrict__ H,          // h_raw [N][320] fp32
    float* __restrict__ st1, float* __restrict__ st2,
    const int M) {

    __shared__ __align__(16) u16 W1s[2][32 * 320];    // 40,960 B
    __shared__ __align__(16) u16 W2s[2][320 * 32];    // 40,960 B
    __shared__ __align__(16) float hidF[2][128 * 36]; // 36,864 B
    __shared__ __align__(16) float biasL[640];        //  2,560 B

    const int tid  = threadIdx.x;
    const int bm   = blockIdx.x * 128;
    const int wave = tid >> 6;
    const int lane = tid & 63;
    const int mg   = wave >> 1;       // 0..3
    const int ng   = wave & 1;        // 0..1
    const int l15  = lane & 15;
    const int q    = lane >> 4;
    const int r7   = l15 & 7;
    const int s2   = (l15 >> 1) & 3;  // W2 read swizzle
    const int sb   = wave * 5;        // flat staging segment base for this wave

    // ---- bias preload (b1 -> LDS; avoids in-loop global loads) ----
    {
        biasL[tid] = (tid < 600) ? b1g[tid] : 0.f;
        int i1 = tid + 512;
        if (i1 < 640) biasL[i1] = (i1 < 600) ? b1g[i1] : 0.f;
    }

    // ---- prologue: W1(0) -> W1s[0] (segs 0..19: waves 0..3, 5 each) ----
    if (sb < 20) {
        #pragma unroll
        for (int k = 0; k < 5; ++k) {
            int i = sb + k;
            gll16(W1t + (size_t)(i * 64 + lane) * 8, &W1s[0][i * 512]);
        }
    }

    // ---- A fragments straight from global (held whole kernel) ----
    bf16x8 afr[2][10];
    #pragma unroll
    for (int mf = 0; mf < 2; ++mf) {
        int arow = bm + mg * 32 + mf * 16 + l15;
        if (arow > M - 1) arow = M - 1;   // tail clamp; rows guarded in epilogue
        const u16* ap = A + (size_t)arow * DP + q * 8;
        #pragma unroll
        for (int kt = 0; kt < 10; ++kt)
            afr[mf][kt] = __builtin_bit_cast(bf16x8, *(const uint4*)(ap + kt * 32));
    }

    f32x4 acc2[2][10];
    const f32x4 zero4 = {0.f, 0.f, 0.f, 0.f};
    #pragma unroll
    for (int mf = 0; mf < 2; ++mf)
        #pragma unroll
        for (int nf = 0; nf < 10; ++nf) acc2[mf][nf] = zero4;

    // full drain once (prologue only)
    asm volatile("s_waitcnt vmcnt(0)" ::: "memory");
    __syncthreads();

    const int rb = (ng * 16 + l15) * 320;   // W1-slice row base for this lane

    for (int c = 0; c < 20; ++c) {
        const int pc = c & 1;

        // ---- phase entry: counted wait + raw barrier (NO vmcnt drain) ----
        if (c) {
            asm volatile("s_waitcnt vmcnt(5) lgkmcnt(0)" ::: "memory");
        } else {
            asm volatile("s_waitcnt lgkmcnt(0)" ::: "memory");
        }
        __builtin_amdgcn_s_barrier();
        __builtin_amdgcn_sched_barrier(0);

        // ---- issue S(c): W1(c+1) segs 0..19, W2(c) segs 20..39 -> parity pc^1 ----
        {
            const u16* g1 = W1t + (size_t)(c + 1) * 10240;
            const u16* g2 = W2t + (size_t)c * 32;
            if (sb < 20) {
                if (c < 19) {
                    #pragma unroll
                    for (int k = 0; k < 5; ++k) {
                        int i = sb + k;
                        gll16(g1 + (size_t)(i * 64 + lane) * 8, &W1s[pc ^ 1][i * 512]);
                    }
                }
            } else {
                #pragma unroll
                for (int k = 0; k < 5; ++k) {
                    int j = sb - 20 + k;
                    int u = j * 64 + lane;      // n = u>>2 (<=319), unit = u&3
                    gll16(g2 + (size_t)(u >> 2) * HP + (u & 3) * 8, &W2s[pc ^ 1][j * 512]);
                }
            }
        }

        __builtin_amdgcn_s_setprio(1);
        // ---- GEMM2(c-1): a2 pack from hidF[pc^1], MFMA with W2s[pc] ----
        if (c > 0) {
            bf16x8 a2[2];
            #pragma unroll
            for (int mf = 0; mf < 2; ++mf) {
                const float* hp = &hidF[pc ^ 1][(mg * 32 + mf * 16 + l15) * 36 + q * 8];
                f32x4 lo = *(const f32x4*)hp;
                f32x4 hi = *(const f32x4*)(hp + 4);
                uint4 w;
                w.x = pack2(lo[0], lo[1]);
                w.y = pack2(lo[2], lo[3]);
                w.z = pack2(hi[0], hi[1]);
                w.w = pack2(hi[2], hi[3]);
                a2[mf] = __builtin_bit_cast(bf16x8, w);
            }
            #pragma unroll
            for (int nf = 0; nf < 10; ++nf) {
                int row = ng * 160 + nf * 16 + l15;
                uint4 t = *(const uint4*)&W2s[pc][row * 32 + ((q ^ s2) << 3)];
                bf16x8 b = __builtin_bit_cast(bf16x8, t);
                acc2[0][nf] = __builtin_amdgcn_mfma_f32_16x16x32_bf16(a2[0], b, acc2[0][nf], 0, 0, 0);
                acc2[1][nf] = __builtin_amdgcn_mfma_f32_16x16x32_bf16(a2[1], b, acc2[1][nf], 0, 0, 0);
            }
        }

        // ---- GEMM1(c): 32 rows (2 mf) x 16 hidden cols, K=320, from W1s[pc] ----
        f32x4 acc1[2] = {zero4, zero4};
        #pragma unroll
        for (int kt = 0; kt < 10; ++kt) {
            uint4 t = *(const uint4*)&W1s[pc][rb + (((kt * 4 + q) ^ r7) << 3)];
            bf16x8 b = __builtin_bit_cast(bf16x8, t);
            acc1[0] = __builtin_amdgcn_mfma_f32_16x16x32_bf16(afr[0][kt], b, acc1[0], 0, 0, 0);
            acc1[1] = __builtin_amdgcn_mfma_f32_16x16x32_bf16(afr[1][kt], b, acc1[1], 0, 0, 0);
        }
        __builtin_amdgcn_s_setprio(0);
        // bias + relu -> hidF[pc] (f32, stride 36: 2-way banks); bias from LDS
        {
            int gcol = c * 32 + ng * 16 + l15;
            float bb = biasL[gcol];
            #pragma unroll
            for (int mf = 0; mf < 2; ++mf)
                #pragma unroll
                for (int r = 0; r < 4; ++r)
                    hidF[pc][(mg * 32 + mf * 16 + q * 4 + r) * 36 + ng * 16 + l15] =
                        fmaxf(acc1[mf][r] + bb, 0.f);
        }
        // no end-of-phase barrier: next phase's entry {vmcnt+lgkm+barrier} covers it
    }

    // ---- post-loop: full drain, then final GEMM2(19) from hidF[1], W2s[0] ----
    asm volatile("s_waitcnt vmcnt(0) lgkmcnt(0)" ::: "memory");
    __builtin_amdgcn_s_barrier();
    __builtin_amdgcn_sched_barrier(0);
    {
        bf16x8 a2[2];
        #pragma unroll
        for (int mf = 0; mf < 2; ++mf) {
            const float* hp = &hidF[1][(mg * 32 + mf * 16 + l15) * 36 + q * 8];
            f32x4 lo = *(const f32x4*)hp;
            f32x4 hi = *(const f32x4*)(hp + 4);
            uint4 w;
            w.x = pack2(lo[0], lo[1]);
            w.y = pack2(lo[2], lo[3]);
            w.z = pack2(hi[0], hi[1]);
            w.w = pack2(hi[2], hi[3]);
            a2[mf] = __builtin_bit_cast(bf16x8, w);
        }
        #pragma unroll
        for (int nf = 0; nf < 10; ++nf) {
            int row = ng * 160 + nf * 16 + l15;
            uint4 t = *(const uint4*)&W2s[0][row * 32 + ((q ^ s2) << 3)];
            bf16x8 b = __builtin_bit_cast(bf16x8, t);
            acc2[0][nf] = __builtin_amdgcn_mfma_f32_16x16x32_bf16(a2[0], b, acc2[0][nf], 0, 0, 0);
            acc2[1][nf] = __builtin_amdgcn_mfma_f32_16x16x32_bf16(a2[1], b, acc2[1][nf], 0, 0, 0);
        }
    }

    // ---- epilogue: bias2, store fp32 raw h, BN stats ----
    #pragma unroll
    for (int nf = 0; nf < 10; ++nf) {
        const int col = ng * 160 + nf * 16 + l15;
        const float bb = (col < 300) ? b2g[col] : 0.f;
        float s1 = 0.f, s2v = 0.f;
        #pragma unroll
        for (int mf = 0; mf < 2; ++mf)
            #pragma unroll
            for (int r = 0; r < 4; ++r) {
                const int row = bm + mg * 32 + mf * 16 + q * 4 + r;
                if (row < M) {
                    float v = acc2[mf][nf][r] + bb;
                    H[(size_t)row * DP + col] = v;
                    s1 += v; s2v += v * v;
                }
            }
        s1 += __shfl_xor(s1, 16); s1 += __shfl_xor(s1, 32);
        s2v += __shfl_xor(s2v, 16); s2v += __shfl_xor(s2v, 32);
        if (q == 0) { atomicAdd(&st1[col], s1); atomicAdd(&st2[col], s2v); }
    }
}

// final: d_out[i][d] = scale[d]*raw[i][d] + shift[d]
__global__ void finalize(const float* __restrict__ hraw, const float* __restrict__ scale,
                         const float* __restrict__ shift, float* __restrict__ out) {
    const int i = blockIdx.x;
    const int d = threadIdx.x;
    if (d < 300) {
        float x = hraw[(size_t)i * DP + d];
        out[(size_t)i * 300 + d] = fmaf(scale[d], x, shift[d]);
    }
}

// ---------------- launcher ----------------
extern "C" void kernel_launch(void* const* d_in, const int* in_sizes, int n_in,
                              void* d_out, int out_size, void* d_ws, size_t ws_size,
                              hipStream_t stream) {
    const int N = NN, E = EE, L = 5;
    const int*   x     = (const int*)d_in[0];
    const int*   ei    = (const int*)d_in[1];
    const int*   ea    = (const int*)d_in[2];
    const float* at    = (const float*)d_in[3];
    const float* bt    = (const float*)d_in[4];
    const float* w1    = (const float*)d_in[5];
    const float* b1    = (const float*)d_in[6];
    const float* w2    = (const float*)d_in[7];
    const float* b2    = (const float*)d_in[8];
    const float* gamma = (const float*)d_in[9];
    const float* beta  = (const float*)d_in[10];
    float* out = (float*)d_out;

    char* ws = (char*)d_ws;
    size_t off = 0;
    auto alloc = [&](size_t bytes) { char* p = ws + off; off = (off + bytes + 255) & ~(size_t)255; return p; };
    u16* buf_y    = (u16*)alloc((size_t)N * DP * 2);     // post-BN/relu state, bf16
    u16* buf_agg  = (u16*)alloc((size_t)N * DP * 2);
    float* buf_h  = (float*)alloc((size_t)N * DP * 4);   // raw (pre-BN) state, fp32
    u16* w1t      = (u16*)alloc((size_t)5 * HP * DP * 2);
    u16* w2t      = (u16*)alloc((size_t)5 * DP * HP * 2);
    int* deg      = (int*)alloc((size_t)N * 4);
    int* offs     = (int*)alloc((size_t)(N + 1) * 4);
    int* cursors  = (int*)alloc((size_t)N * 4);
    u32* vals     = (u32*)alloc((size_t)E * 4);
    int* bsums    = (int*)alloc(128 * 4);
    float* emb    = (float*)alloc(17 * DP * 4);
    float* stats  = (float*)alloc(2 * DP * 4);
    float* scale  = (float*)alloc(DP * 4);
    float* shift  = (float*)alloc(DP * 4);

    // CSR build (once per call; reused by all 5 layers)
    (void)hipMemsetAsync(deg, 0, (size_t)N * 4, stream);
    count_deg<<<(E + 255) / 256, 256, 0, stream>>>(ei, deg, E);
    const int nb = (N + 1023) / 1024;
    scan1<<<nb, 1024, 0, stream>>>(deg, offs, bsums, N);
    scan2<<<1, 128, 0, stream>>>(bsums, nb);
    scan3<<<(N + 1 + 1023) / 1024, 1024, 0, stream>>>(offs, bsums, N, E);
    (void)hipMemcpyAsync(cursors, offs, (size_t)N * 4, hipMemcpyDeviceToDevice, stream);
    fill_csr<<<(E + 255) / 256, 256, 0, stream>>>(ei, ea, cursors, vals, E);

    // weights -> bf16 transposed padded, pre-swizzled images
    conv_w1<<<(5 * HP * DP + 255) / 256, 256, 0, stream>>>(w1, w1t);
    conv_w2<<<(5 * DP * HP + 255) / 256, 256, 0, stream>>>(w2, w2t);

    // layer-0 state
    atom_enc<<<N, DP, 0, stream>>>(x, at, buf_y);

    const int MB = (N + 127) / 128; // 782
    for (int l = 0; l < L; ++l) {
        bond_enc<<<17, DP, 0, stream>>>(bt + (size_t)l * 4 * 6 * 300, emb);
        aggregate<<<(N * 64 + 255) / 256, 256, 0, stream>>>(
            buf_y, emb, offs, vals, buf_agg, N);
        (void)hipMemsetAsync(stats, 0, 2 * DP * 4, stream);
        fused_mlp<<<MB, 512, 0, stream>>>(
            buf_agg,
            w1t + (size_t)l * HP * DP, w2t + (size_t)l * DP * HP,
            b1 + (size_t)l * 600, b2 + (size_t)l * 300,
            buf_h, stats, stats + DP, N);
        bn_ss<<<1, DP, 0, stream>>>(stats, gamma + (size_t)l * 300, beta + (size_t)l * 300, scale, shift, N);
        if (l < L - 1)
            bn_apply<<<N, DP, 0, stream>>>(buf_h, scale, shift, buf_y);
    }
    finalize<<<N, DP, 0, stream>>>(buf_h, scale, shift, out);
}

// Round 9
// 2162.958 us; speedup vs baseline: 1.0185x; 1.0185x over previous
//
#include <hip/hip_runtime.h>

// ---------------- types / helpers ----------------
typedef unsigned short u16;
typedef unsigned int   u32;
typedef __bf16 bf16x8 __attribute__((ext_vector_type(8)));
typedef float  f32x4  __attribute__((ext_vector_type(4)));

__device__ __forceinline__ u16 f2bf(float f) {
    u32 u = __builtin_bit_cast(u32, f);
    u = u + 0x7fffu + ((u >> 16) & 1u);
    return (u16)(u >> 16);
}
__device__ __forceinline__ float bflo(u32 u) { return __builtin_bit_cast(float, u << 16); }
__device__ __forceinline__ float bfhi(u32 u) { return __builtin_bit_cast(float, u & 0xffff0000u); }
__device__ __forceinline__ u32 pack2(float x, float y) { return (u32)f2bf(x) | ((u32)f2bf(y) << 16); }

// global -> LDS direct copy, 16B per lane. LDS dest is wave-uniform base (+lane*16 by HW).
__device__ __forceinline__ void gll16(const u16* g, u16* l) {
    __builtin_amdgcn_global_load_lds(
        (const __attribute__((address_space(1))) void*)g,
        (__attribute__((address_space(3))) void*)l, 16, 0, 0);
}

#define NN 100000
#define MR 100096   // row count padded to 782*128 (no tail logic anywhere)
#define EE 400000
#define DP 320      // padded D (300 -> 320)
#define HP 640      // padded 2D (600 -> 640)

// ---------------- preprocessing ----------------
__global__ void count_deg(const int* __restrict__ ei, int* __restrict__ deg, int E) {
    int e = blockIdx.x * 256 + threadIdx.x;
    if (e < E) atomicAdd(&deg[ei[E + e]], 1);
}

__global__ void scan1(const int* __restrict__ deg, int* __restrict__ out, int* __restrict__ bsums, int n) {
    __shared__ int lds[1024];
    int t = threadIdx.x;
    int i = blockIdx.x * 1024 + t;
    int v = (i < n) ? deg[i] : 0;
    lds[t] = v;
    __syncthreads();
    for (int d = 1; d < 1024; d <<= 1) {
        int add = (t >= d) ? lds[t - d] : 0;
        __syncthreads();
        lds[t] += add;
        __syncthreads();
    }
    if (i < n) out[i] = lds[t] - v;   // exclusive
    if (t == 1023) bsums[blockIdx.x] = lds[t];
}

__global__ void scan2(int* __restrict__ bsums, int nb) {
    __shared__ int lds[128];
    int t = threadIdx.x;
    int v = (t < nb) ? bsums[t] : 0;
    lds[t] = v;
    __syncthreads();
    for (int d = 1; d < 128; d <<= 1) {
        int add = (t >= d) ? lds[t - d] : 0;
        __syncthreads();
        lds[t] += add;
        __syncthreads();
    }
    if (t < nb) bsums[t] = lds[t] - v;
}

__global__ void scan3(int* __restrict__ out, const int* __restrict__ bsums, int n, int etot) {
    int i = blockIdx.x * 1024 + threadIdx.x;
    if (i < n) out[i] += bsums[blockIdx.x];
    else if (i == n) out[i] = etot;
}

__global__ void fill_csr(const int* __restrict__ ei, const int* __restrict__ ea,
                         int* __restrict__ cursors, u32* __restrict__ vals, int E) {
    int e = blockIdx.x * 256 + threadIdx.x;
    if (e >= E) return;
    int dst = ei[E + e];
    int src = ei[e];
    u32 code = (u32)((ea[e*4] & 1) | ((ea[e*4+1] & 1) << 1) | ((ea[e*4+2] & 1) << 2) | ((ea[e*4+3] & 1) << 3));
    int pos = atomicAdd(&cursors[dst], 1);
    vals[pos] = ((u32)src << 4) | code;
}

// W1 -> plain transposed padded bf16: wt[l][n][k] = w1[l][k][n], [5][640][320].
// (No swizzle: BK=32 staging gives 64B row stride in LDS = naturally 2-way banks.)
__global__ void conv_w1(const float* __restrict__ w, u16* __restrict__ wt) {
    int id = blockIdx.x * 256 + threadIdx.x;
    if (id >= 5 * HP * DP) return;
    int l = id / (HP * DP);
    int rem = id - l * (HP * DP);
    int n = rem / DP;
    int k = rem - n * DP;
    u16 v = 0;
    if (n < 600 && k < 300) v = f2bf(w[((size_t)l * 300 + k) * 600 + n]);
    wt[id] = v;
}
// W2 -> plain transposed padded bf16: wt[l][n][k] = w2[l][k][n], [5][384][640].
// (384 = 3 col-blocks of 128 for GEMM2's N=320.)
__global__ void conv_w2(const float* __restrict__ w, u16* __restrict__ wt) {
    int id = blockIdx.x * 256 + threadIdx.x;
    if (id >= 5 * 384 * HP) return;
    int l = id / (384 * HP);
    int rem = id - l * (384 * HP);
    int n = rem / HP;
    int k = rem - n * HP;
    u16 v = 0;
    if (n < 300 && k < 600) v = f2bf(w[((size_t)l * 600 + k) * 300 + n]);
    wt[id] = v;
}

// atom encoder -> y bf16
__global__ void atom_enc(const int* __restrict__ x, const float* __restrict__ at, u16* __restrict__ y) {
    const int i = blockIdx.x;
    const int d = threadIdx.x; // 0..319
    __shared__ int xi[7];
    if (d < 7) xi[d] = x[i * 7 + d];
    __syncthreads();
    u16 v = 0;
    if (d < 300) {
        float s = 0.f;
        #pragma unroll
        for (int f = 0; f < 7; ++f) s += at[(f * 119 + xi[f]) * 300 + d];
        v = f2bf(s);
    }
    y[(size_t)i * DP + d] = v;
}

// per-layer bond embedding table: 16 codes + self-loop (index 16)
__global__ void bond_enc(const float* __restrict__ bt, float* __restrict__ emb) {
    const int c = blockIdx.x;  // 0..16
    const int d = threadIdx.x; // 0..319
    float s = 0.f;
    if (d < 300) {
        if (c < 16) {
            #pragma unroll
            for (int f = 0; f < 4; ++f) s += bt[(f * 6 + ((c >> f) & 1)) * 300 + d];
        } else {
            s = bt[4 * 300 + d];  // bond[0][4]
            #pragma unroll
            for (int f = 1; f < 4; ++f) s += bt[f * 6 * 300 + d];
        }
    }
    emb[c * DP + d] = s;
}

// stats -> BN (scale, shift)
__global__ void bn_ss(const float* __restrict__ stats, const float* __restrict__ gamma,
                      const float* __restrict__ beta, float* __restrict__ scale,
                      float* __restrict__ shift, int n) {
    int d = threadIdx.x;
    float sc = 0.f, sh = 0.f;
    if (d < 300) {
        float inv_n = 1.0f / (float)n;
        float mu = stats[d] * inv_n;
        float var = stats[DP + d] * inv_n - mu * mu;
        float inv = 1.0f / sqrtf(var + 1e-5f);
        sc = gamma[d] * inv;
        sh = beta[d] - mu * sc;
    }
    scale[d] = sc; shift[d] = sh;
}

// y[i][d] = bf16(relu(scale*h_raw + shift))
__global__ void bn_apply(const float* __restrict__ hraw, const float* __restrict__ scale,
                         const float* __restrict__ shift, u16* __restrict__ y) {
    const int i = blockIdx.x;
    const int d = threadIdx.x;
    float v = fmaf(scale[d], hraw[(size_t)i * DP + d], shift[d]);
    y[(size_t)i * DP + d] = f2bf(fmaxf(v, 0.f));
}

// ---------------- aggregation: one wave per node, uint4 gathers ----------------
__global__ void aggregate(const u16* __restrict__ y,
                          const float* __restrict__ emb,
                          const int* __restrict__ offs, const u32* __restrict__ vals,
                          u16* __restrict__ agg, const int n) {
    const int wid = (int)((blockIdx.x * (size_t)blockDim.x + threadIdx.x) >> 6);
    const int lane = threadIdx.x & 63;
    if (wid >= n) return;
    const bool act = (lane < 40);

    float acc[8];
    #pragma unroll
    for (int i = 0; i < 8; ++i) acc[i] = 0.f;

    auto accum = [&](int srcrow, const float* erow) {
        if (act) {
            uint4 v = *(const uint4*)(y + (size_t)srcrow * DP + lane * 8);
            float4 e0 = *(const float4*)(erow + lane * 8);
            float4 e1 = *(const float4*)(erow + lane * 8 + 4);
            acc[0] += bflo(v.x) + e0.x;  acc[1] += bfhi(v.x) + e0.y;
            acc[2] += bflo(v.y) + e0.z;  acc[3] += bfhi(v.y) + e0.w;
            acc[4] += bflo(v.z) + e1.x;  acc[5] += bfhi(v.z) + e1.y;
            acc[6] += bflo(v.w) + e1.z;  acc[7] += bfhi(v.w) + e1.w;
        }
    };

    accum(wid, emb + 16 * DP);            // self loop
    const int s = offs[wid], t = offs[wid + 1];
    for (int e = s; e < t; ++e) {
        u32 v = vals[e];
        accum((int)(v >> 4), emb + (v & 15u) * DP);
    }

    if (act) {
        uint4 o;
        o.x = pack2(acc[0], acc[1]);
        o.y = pack2(acc[2], acc[3]);
        o.z = pack2(acc[4], acc[5]);
        o.w = pack2(acc[6], acc[7]);
        *(uint4*)(agg + (size_t)wid * DP + lane * 8) = o;
    }
}

// ---------------- GEMM1: hid = relu(A @ W1^T + b1), bf16 out ----------------
// m97 structure: 128x128 tile, 4 waves (64x64/wave), BK=32, dbuf LDS 32KB,
// gll16 staging, ONE __syncthreads per K-step.  3 blocks/CU target.
// A: [MR][320] bf16 (pad rows zeroed) ; W1t: [640][320] ; hid: [MR][640].
__global__ __launch_bounds__(256, 3) void gemm1(
    const u16* __restrict__ A, const u16* __restrict__ Bt,
    const float* __restrict__ b1g, u16* __restrict__ hid) {

    __shared__ __align__(16) u16 As[2][128 * 32];   // 16 KB
    __shared__ __align__(16) u16 Bs[2][128 * 32];   // 16 KB

    const int tid  = threadIdx.x;
    const int wave = tid >> 6;
    const int lane = tid & 63;
    const int l15  = lane & 15;
    const int q    = lane >> 4;
    const int wr   = wave >> 1, wc = wave & 1;
    const int bn   = blockIdx.x % 5;
    const size_t bm = (size_t)(blockIdx.x / 5) * 128;
    const int srow = lane >> 2;          // 0..15
    const int scol = (lane & 3) * 8;     // u16 units

    f32x4 acc[4][4];
    const f32x4 zero4 = {0.f, 0.f, 0.f, 0.f};
    #pragma unroll
    for (int mi = 0; mi < 4; ++mi)
        #pragma unroll
        for (int ni = 0; ni < 4; ++ni) acc[mi][ni] = zero4;

    auto stage = [&](int buf, int k0) {
        #pragma unroll
        for (int t = 0; t < 2; ++t) {
            int s = wave + t * 4;        // 0..7
            gll16(A + (bm + s * 16 + srow) * DP + k0 + scol, &As[buf][s * 512]);
        }
        #pragma unroll
        for (int t = 0; t < 2; ++t) {
            int s = wave + t * 4;
            gll16(Bt + (size_t)(bn * 128 + s * 16 + srow) * DP + k0 + scol, &Bs[buf][s * 512]);
        }
    };

    stage(0, 0);
    __syncthreads();

    for (int ks = 0; ks < 10; ++ks) {
        const int cur = ks & 1;
        if (ks < 9) stage(cur ^ 1, (ks + 1) * 32);
        bf16x8 af[4], bf[4];
        #pragma unroll
        for (int i = 0; i < 4; ++i) {
            af[i] = __builtin_bit_cast(bf16x8, *(const uint4*)&As[cur][(wr * 64 + i * 16 + l15) * 32 + q * 8]);
            bf[i] = __builtin_bit_cast(bf16x8, *(const uint4*)&Bs[cur][(wc * 64 + i * 16 + l15) * 32 + q * 8]);
        }
        #pragma unroll
        for (int mi = 0; mi < 4; ++mi)
            #pragma unroll
            for (int ni = 0; ni < 4; ++ni)
                acc[mi][ni] = __builtin_amdgcn_mfma_f32_16x16x32_bf16(af[mi], bf[ni], acc[mi][ni], 0, 0, 0);
        __syncthreads();   // drains staged loads + protects dbuf reuse
    }

    // epilogue: bias + relu -> bf16 (cols < 640 always in-range; pad rows harmless)
    #pragma unroll
    for (int ni = 0; ni < 4; ++ni) {
        const int col = bn * 128 + wc * 64 + ni * 16 + l15;
        const float bb = (col < 600) ? b1g[col] : 0.f;
        #pragma unroll
        for (int mi = 0; mi < 4; ++mi)
            #pragma unroll
            for (int r = 0; r < 4; ++r) {
                size_t row = bm + wr * 64 + mi * 16 + q * 4 + r;
                hid[row * HP + col] = f2bf(fmaxf(acc[mi][ni][r] + bb, 0.f));
            }
    }
}

// ---------------- GEMM2: H = hid @ W2^T + b2 (fp32) + BN stats ----------------
// Same structure, K=640 (20 steps), N=320 -> 3 col-blocks (Bt padded to 384 rows).
__global__ __launch_bounds__(256, 3) void gemm2(
    const u16* __restrict__ A /*hid*/, const u16* __restrict__ Bt /*w2t [384][640]*/,
    const float* __restrict__ b2g, float* __restrict__ H,
    float* __restrict__ st1, float* __restrict__ st2, const int M) {

    __shared__ __align__(16) u16 As[2][128 * 32];
    __shared__ __align__(16) u16 Bs[2][128 * 32];

    const int tid  = threadIdx.x;
    const int wave = tid >> 6;
    const int lane = tid & 63;
    const int l15  = lane & 15;
    const int q    = lane >> 4;
    const int wr   = wave >> 1, wc = wave & 1;
    const int bn   = blockIdx.x % 3;
    const size_t bm = (size_t)(blockIdx.x / 3) * 128;
    const int srow = lane >> 2;
    const int scol = (lane & 3) * 8;

    f32x4 acc[4][4];
    const f32x4 zero4 = {0.f, 0.f, 0.f, 0.f};
    #pragma unroll
    for (int mi = 0; mi < 4; ++mi)
        #pragma unroll
        for (int ni = 0; ni < 4; ++ni) acc[mi][ni] = zero4;

    auto stage = [&](int buf, int k0) {
        #pragma unroll
        for (int t = 0; t < 2; ++t) {
            int s = wave + t * 4;
            gll16(A + (bm + s * 16 + srow) * HP + k0 + scol, &As[buf][s * 512]);
        }
        #pragma unroll
        for (int t = 0; t < 2; ++t) {
            int s = wave + t * 4;
            gll16(Bt + (size_t)(bn * 128 + s * 16 + srow) * HP + k0 + scol, &Bs[buf][s * 512]);
        }
    };

    stage(0, 0);
    __syncthreads();

    for (int ks = 0; ks < 20; ++ks) {
        const int cur = ks & 1;
        if (ks < 19) stage(cur ^ 1, (ks + 1) * 32);
        bf16x8 af[4], bf[4];
        #pragma unroll
        for (int i = 0; i < 4; ++i) {
            af[i] = __builtin_bit_cast(bf16x8, *(const uint4*)&As[cur][(wr * 64 + i * 16 + l15) * 32 + q * 8]);
            bf[i] = __builtin_bit_cast(bf16x8, *(const uint4*)&Bs[cur][(wc * 64 + i * 16 + l15) * 32 + q * 8]);
        }
        #pragma unroll
        for (int mi = 0; mi < 4; ++mi)
            #pragma unroll
            for (int ni = 0; ni < 4; ++ni)
                acc[mi][ni] = __builtin_amdgcn_mfma_f32_16x16x32_bf16(af[mi], bf[ni], acc[mi][ni], 0, 0, 0);
        __syncthreads();
    }

    // epilogue: bias2, fp32 store (col<320, row<M), BN stats (col<300, row<M)
    #pragma unroll
    for (int ni = 0; ni < 4; ++ni) {
        const int col = bn * 128 + wc * 64 + ni * 16 + l15;   // 0..383
        const bool cok = (col < DP);
        const float bb = (col < 300) ? b2g[col] : 0.f;
        float s1 = 0.f, s2 = 0.f;
        #pragma unroll
        for (int mi = 0; mi < 4; ++mi)
            #pragma unroll
            for (int r = 0; r < 4; ++r) {
                size_t row = bm + wr * 64 + mi * 16 + q * 4 + r;
                if (cok && row < (size_t)M) {
                    float v = acc[mi][ni][r] + bb;
                    H[row * DP + col] = v;
                    s1 += v; s2 += v * v;
                }
            }
        s1 += __shfl_xor(s1, 16); s1 += __shfl_xor(s1, 32);
        s2 += __shfl_xor(s2, 16); s2 += __shfl_xor(s2, 32);
        if (q == 0 && col < 300) { atomicAdd(&st1[col], s1); atomicAdd(&st2[col], s2); }
    }
}

// final: d_out[i][d] = scale[d]*raw[i][d] + shift[d]
__global__ void finalize(const float* __restrict__ hraw, const float* __restrict__ scale,
                         const float* __restrict__ shift, float* __restrict__ out) {
    const int i = blockIdx.x;
    const int d = threadIdx.x;
    if (d < 300) {
        float x = hraw[(size_t)i * DP + d];
        out[(size_t)i * 300 + d] = fmaf(scale[d], x, shift[d]);
    }
}

// ---------------- launcher ----------------
extern "C" void kernel_launch(void* const* d_in, const int* in_sizes, int n_in,
                              void* d_out, int out_size, void* d_ws, size_t ws_size,
                              hipStream_t stream) {
    const int N = NN, E = EE, L = 5;
    const int*   x     = (const int*)d_in[0];
    const int*   ei    = (const int*)d_in[1];
    const int*   ea    = (const int*)d_in[2];
    const float* at    = (const float*)d_in[3];
    const float* bt    = (const float*)d_in[4];
    const float* w1    = (const float*)d_in[5];
    const float* b1    = (const float*)d_in[6];
    const float* w2    = (const float*)d_in[7];
    const float* b2    = (const float*)d_in[8];
    const float* gamma = (const float*)d_in[9];
    const float* beta  = (const float*)d_in[10];
    float* out = (float*)d_out;

    char* ws = (char*)d_ws;
    size_t off = 0;
    auto alloc = [&](size_t bytes) { char* p = ws + off; off = (off + bytes + 255) & ~(size_t)255; return p; };
    u16* buf_y    = (u16*)alloc((size_t)MR * DP * 2);    // post-BN/relu state, bf16
    u16* buf_agg  = (u16*)alloc((size_t)MR * DP * 2);    // aggregated, bf16 (pad rows zeroed)
    u16* buf_hid  = (u16*)alloc((size_t)MR * HP * 2);    // hidden activations, bf16
    float* buf_h  = (float*)alloc((size_t)MR * DP * 4);  // raw (pre-BN) state, fp32
    u16* w1t      = (u16*)alloc((size_t)5 * HP * DP * 2);
    u16* w2t      = (u16*)alloc((size_t)5 * 384 * HP * 2);
    int* deg      = (int*)alloc((size_t)N * 4);
    int* offs     = (int*)alloc((size_t)(N + 1) * 4);
    int* cursors  = (int*)alloc((size_t)N * 4);
    u32* vals     = (u32*)alloc((size_t)E * 4);
    int* bsums    = (int*)alloc(128 * 4);
    float* emb    = (float*)alloc(17 * DP * 4);
    float* stats  = (float*)alloc(2 * DP * 4);
    float* scale  = (float*)alloc(DP * 4);
    float* shift  = (float*)alloc(DP * 4);

    // zero the A pad rows once: GEMM1 then always reads zeros there
    (void)hipMemsetAsync(buf_agg + (size_t)N * DP, 0, (size_t)(MR - N) * DP * 2, stream);

    // CSR build (once per call; reused by all 5 layers)
    (void)hipMemsetAsync(deg, 0, (size_t)N * 4, stream);
    count_deg<<<(E + 255) / 256, 256, 0, stream>>>(ei, deg, E);
    const int nb = (N + 1023) / 1024;
    scan1<<<nb, 1024, 0, stream>>>(deg, offs, bsums, N);
    scan2<<<1, 128, 0, stream>>>(bsums, nb);
    scan3<<<(N + 1 + 1023) / 1024, 1024, 0, stream>>>(offs, bsums, N, E);
    (void)hipMemcpyAsync(cursors, offs, (size_t)N * 4, hipMemcpyDeviceToDevice, stream);
    fill_csr<<<(E + 255) / 256, 256, 0, stream>>>(ei, ea, cursors, vals, E);

    // weights -> bf16 transposed padded (plain, unswizzled)
    conv_w1<<<(5 * HP * DP + 255) / 256, 256, 0, stream>>>(w1, w1t);
    conv_w2<<<(5 * 384 * HP + 255) / 256, 256, 0, stream>>>(w2, w2t);

    // layer-0 state
    atom_enc<<<N, DP, 0, stream>>>(x, at, buf_y);

    const int MB = MR / 128; // 782
    for (int l = 0; l < L; ++l) {
        bond_enc<<<17, DP, 0, stream>>>(bt + (size_t)l * 4 * 6 * 300, emb);
        aggregate<<<(N * 64 + 255) / 256, 256, 0, stream>>>(
            buf_y, emb, offs, vals, buf_agg, N);
        (void)hipMemsetAsync(stats, 0, 2 * DP * 4, stream);
        gemm1<<<MB * 5, 256, 0, stream>>>(
            buf_agg, w1t + (size_t)l * HP * DP, b1 + (size_t)l * 600, buf_hid);
        gemm2<<<MB * 3, 256, 0, stream>>>(
            buf_hid, w2t + (size_t)l * 384 * HP, b2 + (size_t)l * 300,
            buf_h, stats, stats + DP, N);
        bn_ss<<<1, DP, 0, stream>>>(stats, gamma + (size_t)l * 300, beta + (size_t)l * 300, scale, shift, N);
        if (l < L - 1)
            bn_apply<<<N, DP, 0, stream>>>(buf_h, scale, shift, buf_y);
    }
    finalize<<<N, DP, 0, stream>>>(buf_h, scale, shift, out);
}